// Round 5
// baseline (421.368 us; speedup 1.0000x reference)
//
#include <hip/hip_runtime.h>
#include <stdint.h>

// ---- problem constants -----------------------------------------------------
#define N_TOK   8192
#define DIMK    1024      // D == H == 1024
#define NEXP    8
#define PADROWS 18432     // 16384 assignments + up to 8*256 padding, 256-aligned

typedef __attribute__((ext_vector_type(8))) short short8;   // 8 bf16 (4 VGPRs)
typedef __attribute__((ext_vector_type(4))) float f32x4;    // MFMA accumulator
typedef unsigned short u16;

__device__ __forceinline__ u16 f2bf(float f) {              // RNE f32->bf16
  uint32_t u = __builtin_bit_cast(uint32_t, f);
  u += 0x7fffu + ((u >> 16) & 1u);
  return (u16)(u >> 16);
}

__device__ __forceinline__ void load16_lds(const void* g, void* l) {
  __builtin_amdgcn_global_load_lds(
      (const __attribute__((address_space(1))) void*)g,
      (__attribute__((address_space(3))) void*)l, 16, 0, 0);
}

// ---- workspace layout (bytes) ----------------------------------------------
#define OFF_W1T   0u
#define OFF_W2T   16777216u
#define OFF_XP    33554432u          // 18432*1024*2 = 37,748,736
#define OFF_H1    71303168u          // 37,748,736
#define OFF_GIDX  109051904u         // 65,536
#define OFF_GVAL  109117440u         // 65,536
#define OFF_PTOK  109182976u         // 73,728
#define OFF_PGATE 109256704u         // 73,728
#define OFF_CTRL  109330432u         // 512
// zero region each launch: ptok+pgate+ctrl = 73728+73728+512 = 147,968 B

// ---- W transpose+convert via LDS tile: WT[e][n][k] = bf16(W[e][k][n]) ------
__global__ void convw_kernel(const float* __restrict__ W1, const float* __restrict__ W2,
                             u16* __restrict__ W1T, u16* __restrict__ W2T) {
  __shared__ u16 tile[64][65];
  int b = (int)blockIdx.x;
  const float* src = W1; u16* dst = W1T;
  if (b >= 2048) { src = W2; dst = W2T; b -= 2048; }
  const int e  = b >> 8;
  const int t  = b & 255;
  const int k0 = (t >> 4) << 6;
  const int n0 = (t & 15) << 6;
  const int tid = (int)threadIdx.x;
  const int r  = tid >> 2;
  const int c4 = (tid & 3) << 4;
  const float4* s = (const float4*)(src + ((size_t)e << 20) +
                                    ((size_t)(k0 + r) << 10) + n0 + c4);
#pragma unroll
  for (int j = 0; j < 4; ++j) {
    float4 v = s[j];
    tile[r][c4 + 4 * j + 0] = f2bf(v.x);
    tile[r][c4 + 4 * j + 1] = f2bf(v.y);
    tile[r][c4 + 4 * j + 2] = f2bf(v.z);
    tile[r][c4 + 4 * j + 3] = f2bf(v.w);
  }
  __syncthreads();
  const int on = tid >> 2;
  const int ok = (tid & 3) << 4;
  u16* d = dst + ((size_t)e << 20) + ((size_t)(n0 + on) << 10) + k0 + ok;
  short8 v0, v1;
#pragma unroll
  for (int j = 0; j < 8; ++j) {
    v0[j] = (short)tile[ok + j][on];
    v1[j] = (short)tile[ok + 8 + j][on];
  }
  *(short8*)d = v0;
  *(short8*)(d + 8) = v1;
}

// ---- gating: f32 logits, top-2 (jax tie-break), softmax, histogram ---------
__global__ void gate_kernel(const float* __restrict__ x, const float* __restrict__ Wg,
                            const float* __restrict__ bg, int* __restrict__ gidx,
                            float* __restrict__ gval, int* __restrict__ counts) {
  __shared__ int hist[NEXP];
  const int tid = (int)threadIdx.x;
  if (tid < NEXP) hist[tid] = 0;
  __syncthreads();
  const int n = (int)blockIdx.x * 4 + (tid >> 6);
  const int lane = tid & 63;
  float acc[NEXP];
#pragma unroll
  for (int e = 0; e < NEXP; ++e) acc[e] = 0.f;
  const float4* xr = (const float4*)(x + ((size_t)n << 10));
#pragma unroll
  for (int j = 0; j < 4; ++j) {
    float4 xv = xr[j * 64 + lane];
#pragma unroll
    for (int e = 0; e < NEXP; ++e) {
      float4 wv = ((const float4*)(Wg + ((size_t)e << 10)))[j * 64 + lane];
      acc[e] += xv.x * wv.x + xv.y * wv.y + xv.z * wv.z + xv.w * wv.w;
    }
  }
#pragma unroll
  for (int e = 0; e < NEXP; ++e)
#pragma unroll
    for (int off = 32; off; off >>= 1) acc[e] += __shfl_xor(acc[e], off, 64);
  if (lane == 0) {
    float lg[NEXP];
#pragma unroll
    for (int e = 0; e < NEXP; ++e) lg[e] = acc[e] + bg[e];
    int e0 = 0; float v0 = lg[0];
#pragma unroll
    for (int e = 1; e < NEXP; ++e) if (lg[e] > v0) { v0 = lg[e]; e0 = e; }
    int e1 = -1; float v1 = -1e30f;
#pragma unroll
    for (int e = 0; e < NEXP; ++e) if (e != e0 && lg[e] > v1) { v1 = lg[e]; e1 = e; }
    float t = expf(v1 - v0);            // v0 >= v1
    float g0 = 1.f / (1.f + t);
    gidx[2 * n] = e0; gidx[2 * n + 1] = e1;
    gval[2 * n] = g0; gval[2 * n + 1] = t * g0;
    atomicAdd(&hist[e0], 1); atomicAdd(&hist[e1], 1);
  }
  __syncthreads();
  if (tid < NEXP && hist[tid]) atomicAdd(&counts[tid], hist[tid]);
}

// ---- scan: 256-aligned segment offsets -------------------------------------
__global__ void scan_kernel(const int* __restrict__ counts, int* __restrict__ poff) {
  if (threadIdx.x == 0) {
    int off = 0; poff[0] = 0;
    for (int e = 0; e < NEXP; ++e) { off += ((counts[e] + 255) >> 8) << 8; poff[e + 1] = off; }
  }
}

// ---- scatter assignments into expert segments ------------------------------
__global__ void scatter_kernel(const int* __restrict__ gidx, const float* __restrict__ gval,
                               const int* __restrict__ poff, int* __restrict__ cursor,
                               int* __restrict__ ptok, float* __restrict__ pgate) {
  const int n = (int)blockIdx.x * 256 + (int)threadIdx.x;
#pragma unroll
  for (int k = 0; k < 2; ++k) {
    const int e = gidx[2 * n + k];
    const int p = poff[e] + atomicAdd(&cursor[e], 1);
    ptok[p] = n;
    pgate[p] = gval[2 * n + k];
  }
}

// ---- gather x rows (permuted) -> bf16 --------------------------------------
__global__ void gather_kernel(const float* __restrict__ x, const int* __restrict__ ptok,
                              u16* __restrict__ xp) {
  const int p = (int)blockIdx.x * 4 + ((int)threadIdx.x >> 6);
  const int lane = (int)threadIdx.x & 63;
  const int tok = ptok[p];
  const float4* src = (const float4*)(x + ((size_t)tok << 10));
  ushort4* dst = (ushort4*)(xp + ((size_t)p << 10));
#pragma unroll
  for (int j = 0; j < 4; ++j) {
    float4 v = src[j * 64 + lane];
    ushort4 o; o.x = f2bf(v.x); o.y = f2bf(v.y); o.z = f2bf(v.z); o.w = f2bf(v.w);
    dst[j * 64 + lane] = o;
  }
}

// ---- grouped GEMM: 256x256 tile, BK=64, 8 waves (2M x 4N), 2-phase dbuf ----
// ONE variable changed vs R3: tile 128^2 -> 256^2 (m248v2: 2ph 256^2 K=1024
// grouped = 655 TF at exactly this shape). Two separate dispatches (kernel
// boundary = coherence; no spins). Per-wave output 128x64 (acc[8][4] f32x4).
// 2-phase: STAGE(kt+1) BEFORE COMPUTE(kt), one __syncthreads per K-tile;
// buffer indices compile-time via unroll. T2 swizzle both-sides as before.
template <int PASS>
__global__ __launch_bounds__(512, 2)
void gemm_kernel(const u16* __restrict__ A, const u16* __restrict__ WT,
                 const float* __restrict__ bias, const int* __restrict__ poff,
                 const int* __restrict__ ptok, const float* __restrict__ pgate,
                 u16* __restrict__ Hout, float* __restrict__ Out) {
  __shared__ u16 As[2][256 * 64];
  __shared__ u16 Bs[2][256 * 64];
  __shared__ int tokS[256];
  __shared__ float gateS[256];

  const int nrt = poff[NEXP] >> 8;       // 256-row tiles
  const int rt = (int)blockIdx.x >> 2;
  if (rt >= nrt) return;
  const int ct = (int)blockIdx.x & 3;

  const int tid = (int)threadIdx.x;
  const int lane = tid & 63;
  const int wid = tid >> 6;              // 0..7
  const int wm = (wid >> 2) * 128;       // wave M origin
  const int wn = (wid & 3) * 64;         // wave N origin
  const int r_in = lane >> 3;            // row within 8-row chunk
  const int s_phys = lane & 7;           // physical 16B slot

  const int row0 = rt << 8;
  int e = 0;
  while (row0 >= poff[e + 1]) ++e;       // 256-aligned segments: no spanning

  const u16* Ab = A + ((size_t)row0 << 10);
  const u16* Wb = WT + ((size_t)e << 20) + ((size_t)(ct << 8) << 10);

  if (PASS == 2 && tid < 256) {
    tokS[tid] = ptok[row0 + tid];
    gateS[tid] = pgate[row0 + tid];
  }

  f32x4 acc[8][4] = {};

#define STAGE(BUF, K0)                                                         \
  {                                                                            \
    _Pragma("unroll")                                                          \
    for (int i = 0; i < 4; ++i) {                                              \
      const int chunk = wid * 4 + i;          /* 32 chunks x 1KB per matrix */ \
      const int row = chunk * 8 + r_in;                                        \
      const int slotL = s_phys ^ (row & 7);                                    \
      const size_t goff = ((size_t)row << 10) + (size_t)((K0) + slotL * 8);    \
      load16_lds(Ab + goff, &As[BUF][chunk * 512]);                            \
      load16_lds(Wb + goff, &Bs[BUF][chunk * 512]);                            \
    }                                                                          \
  }

#define COMPUTE(BUF)                                                           \
  {                                                                            \
    _Pragma("unroll")                                                          \
    for (int kk = 0; kk < 2; ++kk) {                                           \
      short8 af[8], bf_[4];                                                    \
      const int kslot = kk * 4 + (lane >> 4);                                  \
      _Pragma("unroll")                                                        \
      for (int mi = 0; mi < 8; ++mi) {                                         \
        const int m = wm + mi * 16 + (lane & 15);                              \
        af[mi] = *(const short8*)((const char*)&As[BUF][0] + m * 128 +         \
                                  ((kslot ^ (m & 7)) << 4));                   \
      }                                                                        \
      _Pragma("unroll")                                                        \
      for (int ni = 0; ni < 4; ++ni) {                                         \
        const int n = wn + ni * 16 + (lane & 15);                              \
        bf_[ni] = *(const short8*)((const char*)&Bs[BUF][0] + n * 128 +        \
                                   ((kslot ^ (n & 7)) << 4));                  \
      }                                                                        \
      _Pragma("unroll")                                                        \
      for (int mi = 0; mi < 8; ++mi)                                           \
        _Pragma("unroll")                                                      \
        for (int ni = 0; ni < 4; ++ni)                                         \
          acc[mi][ni] = __builtin_amdgcn_mfma_f32_16x16x32_bf16(               \
              af[mi], bf_[ni], acc[mi][ni], 0, 0, 0);                          \
    }                                                                          \
  }

  STAGE(0, 0)
  __syncthreads();
#pragma unroll 2
  for (int kt = 0; kt < 16; ++kt) {
    if (kt < 15) STAGE((kt + 1) & 1, (kt + 1) * 64)  // fly under compute
    COMPUTE(kt & 1)
    __syncthreads();     // loads landed + reads done: swap buffers
  }

  // epilogue: C/D layout col = lane&15, row = (lane>>4)*4 + j  [m89/m91]
  const float* bb = bias + (e << 10) + (ct << 8);
  const int cbase = lane & 15;
  const int rbase = (lane >> 4) * 4;
#pragma unroll
  for (int ni = 0; ni < 4; ++ni) {
    const int col = wn + ni * 16 + cbase;
    const float bv = bb[col];
#pragma unroll
    for (int mi = 0; mi < 8; ++mi) {
      const int mb = wm + mi * 16 + rbase;
#pragma unroll
      for (int j = 0; j < 4; ++j) {
        float v = fmaxf(acc[mi][ni][j] + bv, 0.0f);
        if (PASS == 1) {
          Hout[((size_t)(row0 + mb + j) << 10) + (size_t)((ct << 8) + col)] = f2bf(v);
        } else {
          const int m = mb + j;   // pad rows: gate==0 -> adds exactly 0
          unsafeAtomicAdd(Out + ((size_t)tokS[m] << 10) + (size_t)((ct << 8) + col),
                          v * gateS[m]);
        }
      }
    }
  }
#undef STAGE
#undef COMPUTE
}

// ---- host-side launch ------------------------------------------------------
extern "C" void kernel_launch(void* const* d_in, const int* in_sizes, int n_in,
                              void* d_out, int out_size, void* d_ws, size_t ws_size,
                              hipStream_t stream) {
  (void)in_sizes; (void)n_in; (void)ws_size;
  const float* x  = (const float*)d_in[0];
  const float* W1 = (const float*)d_in[1];
  const float* b1 = (const float*)d_in[2];
  const float* W2 = (const float*)d_in[3];
  const float* b2 = (const float*)d_in[4];
  const float* Wg = (const float*)d_in[5];
  const float* bg = (const float*)d_in[6];
  float* out = (float*)d_out;
  char* ws = (char*)d_ws;

  u16*   W1T   = (u16*)(ws + OFF_W1T);
  u16*   W2T   = (u16*)(ws + OFF_W2T);
  u16*   xp    = (u16*)(ws + OFF_XP);
  u16*   h1    = (u16*)(ws + OFF_H1);
  int*   gidx  = (int*)(ws + OFF_GIDX);
  float* gval  = (float*)(ws + OFF_GVAL);
  int*   ptok  = (int*)(ws + OFF_PTOK);
  float* pgate = (float*)(ws + OFF_PGATE);
  int*   counts = (int*)(ws + OFF_CTRL);
  int*   cursor = counts + 8;
  int*   poff   = counts + 16;   // 9 ints

  hipMemsetAsync(d_out, 0, (size_t)out_size * 4, stream);
  hipMemsetAsync(ws + OFF_PTOK, 0, 147968, stream);

  convw_kernel<<<4096, 256, 0, stream>>>(W1, W2, W1T, W2T);
  gate_kernel<<<N_TOK / 4, 256, 0, stream>>>(x, Wg, bg, gidx, gval, counts);
  scan_kernel<<<1, 64, 0, stream>>>(counts, poff);
  scatter_kernel<<<N_TOK / 256, 256, 0, stream>>>(gidx, gval, poff, cursor, ptok, pgate);
  gather_kernel<<<PADROWS / 4, 256, 0, stream>>>(x, ptok, xp);
  gemm_kernel<1><<<288, 512, 0, stream>>>(xp, W1T, b1, poff, ptok, pgate, h1, nullptr);
  gemm_kernel<2><<<288, 512, 0, stream>>>(h1, W2T, b2, poff, ptok, pgate, nullptr, out);
}

// Round 6
// 374.710 us; speedup vs baseline: 1.1245x; 1.1245x over previous
//
#include <hip/hip_runtime.h>
#include <stdint.h>

// ---- problem constants -----------------------------------------------------
#define N_TOK   8192
#define DIMK    1024      // D == H == 1024
#define NEXP    8
#define PADROWS 17408     // 16384 assignments + up to 8*128 padding, 128-aligned
#define MAXRT   136       // max row tiles of 128

typedef __attribute__((ext_vector_type(8))) short short8;   // 8 bf16 (4 VGPRs)
typedef __attribute__((ext_vector_type(4))) float f32x4;    // MFMA accumulator
typedef unsigned short u16;

__device__ __forceinline__ u16 f2bf(float f) {              // RNE f32->bf16
  uint32_t u = __builtin_bit_cast(uint32_t, f);
  u += 0x7fffu + ((u >> 16) & 1u);
  return (u16)(u >> 16);
}

__device__ __forceinline__ void load16_lds(const void* g, void* l) {
  __builtin_amdgcn_global_load_lds(
      (const __attribute__((address_space(1))) void*)g,
      (__attribute__((address_space(3))) void*)l, 16, 0, 0);
}

// ---- workspace layout (bytes) ----------------------------------------------
#define OFF_W1T   0u
#define OFF_W2T   16777216u
#define OFF_XP    33554432u
#define OFF_H1    69206016u
#define OFF_GIDX  104857600u
#define OFF_GVAL  104923136u
#define OFF_PTOK  104988672u
#define OFF_PGATE 105058304u
#define OFF_CTRL  105127936u
// zero region each launch: ptok + pgate + ctrl = 69632+69632+128 = 139392 B

// ---- W transpose+convert via LDS tile: WT[e][n][k] = bf16(W[e][k][n]) ------
__global__ void convw_kernel(const float* __restrict__ W1, const float* __restrict__ W2,
                             u16* __restrict__ W1T, u16* __restrict__ W2T) {
  __shared__ u16 tile[64][65];
  int b = (int)blockIdx.x;
  const float* src = W1; u16* dst = W1T;
  if (b >= 2048) { src = W2; dst = W2T; b -= 2048; }
  const int e  = b >> 8;
  const int t  = b & 255;
  const int k0 = (t >> 4) << 6;
  const int n0 = (t & 15) << 6;
  const int tid = (int)threadIdx.x;
  const int r  = tid >> 2;
  const int c4 = (tid & 3) << 4;
  const float4* s = (const float4*)(src + ((size_t)e << 20) +
                                    ((size_t)(k0 + r) << 10) + n0 + c4);
#pragma unroll
  for (int j = 0; j < 4; ++j) {
    float4 v = s[j];
    tile[r][c4 + 4 * j + 0] = f2bf(v.x);
    tile[r][c4 + 4 * j + 1] = f2bf(v.y);
    tile[r][c4 + 4 * j + 2] = f2bf(v.z);
    tile[r][c4 + 4 * j + 3] = f2bf(v.w);
  }
  __syncthreads();
  const int on = tid >> 2;
  const int ok = (tid & 3) << 4;
  u16* d = dst + ((size_t)e << 20) + ((size_t)(n0 + on) << 10) + k0 + ok;
  short8 v0, v1;
#pragma unroll
  for (int j = 0; j < 8; ++j) {
    v0[j] = (short)tile[ok + j][on];
    v1[j] = (short)tile[ok + 8 + j][on];
  }
  *(short8*)d = v0;
  *(short8*)(d + 8) = v1;
}

// ---- gating: f32 logits, top-2 (jax tie-break), softmax, histogram ---------
__global__ void gate_kernel(const float* __restrict__ x, const float* __restrict__ Wg,
                            const float* __restrict__ bg, int* __restrict__ gidx,
                            float* __restrict__ gval, int* __restrict__ counts) {
  __shared__ int hist[NEXP];
  const int tid = (int)threadIdx.x;
  if (tid < NEXP) hist[tid] = 0;
  __syncthreads();
  const int n = (int)blockIdx.x * 4 + (tid >> 6);
  const int lane = tid & 63;
  float acc[NEXP];
#pragma unroll
  for (int e = 0; e < NEXP; ++e) acc[e] = 0.f;
  const float4* xr = (const float4*)(x + ((size_t)n << 10));
#pragma unroll
  for (int j = 0; j < 4; ++j) {
    float4 xv = xr[j * 64 + lane];
#pragma unroll
    for (int e = 0; e < NEXP; ++e) {
      float4 wv = ((const float4*)(Wg + ((size_t)e << 10)))[j * 64 + lane];
      acc[e] += xv.x * wv.x + xv.y * wv.y + xv.z * wv.z + xv.w * wv.w;
    }
  }
#pragma unroll
  for (int e = 0; e < NEXP; ++e)
#pragma unroll
    for (int off = 32; off; off >>= 1) acc[e] += __shfl_xor(acc[e], off, 64);
  if (lane == 0) {
    float lg[NEXP];
#pragma unroll
    for (int e = 0; e < NEXP; ++e) lg[e] = acc[e] + bg[e];
    int e0 = 0; float v0 = lg[0];
#pragma unroll
    for (int e = 1; e < NEXP; ++e) if (lg[e] > v0) { v0 = lg[e]; e0 = e; }
    int e1 = -1; float v1 = -1e30f;
#pragma unroll
    for (int e = 0; e < NEXP; ++e) if (e != e0 && lg[e] > v1) { v1 = lg[e]; e1 = e; }
    float t = expf(v1 - v0);            // v0 >= v1
    float g0 = 1.f / (1.f + t);
    gidx[2 * n] = e0; gidx[2 * n + 1] = e1;
    gval[2 * n] = g0; gval[2 * n + 1] = t * g0;
    atomicAdd(&hist[e0], 1); atomicAdd(&hist[e1], 1);
  }
  __syncthreads();
  if (tid < NEXP && hist[tid]) atomicAdd(&counts[tid], hist[tid]);
}

// ---- scan: 128-aligned segment offsets -------------------------------------
__global__ void scan_kernel(const int* __restrict__ counts, int* __restrict__ poff) {
  if (threadIdx.x == 0) {
    int off = 0; poff[0] = 0;
    for (int e = 0; e < NEXP; ++e) { off += ((counts[e] + 127) >> 7) << 7; poff[e + 1] = off; }
  }
}

// ---- scatter assignments into expert segments ------------------------------
__global__ void scatter_kernel(const int* __restrict__ gidx, const float* __restrict__ gval,
                               const int* __restrict__ poff, int* __restrict__ cursor,
                               int* __restrict__ ptok, float* __restrict__ pgate) {
  const int n = (int)blockIdx.x * 256 + (int)threadIdx.x;
#pragma unroll
  for (int k = 0; k < 2; ++k) {
    const int e = gidx[2 * n + k];
    const int p = poff[e] + atomicAdd(&cursor[e], 1);
    ptok[p] = n;
    pgate[p] = gval[2 * n + k];
  }
}

// ---- gather x rows (permuted) -> bf16 --------------------------------------
__global__ void gather_kernel(const float* __restrict__ x, const int* __restrict__ ptok,
                              u16* __restrict__ xp) {
  const int p = (int)blockIdx.x * 4 + ((int)threadIdx.x >> 6);
  const int lane = (int)threadIdx.x & 63;
  const int tok = ptok[p];
  const float4* src = (const float4*)(x + ((size_t)tok << 10));
  ushort4* dst = (ushort4*)(xp + ((size_t)p << 10));
#pragma unroll
  for (int j = 0; j < 4; ++j) {
    float4 v = src[j * 64 + lane];
    ushort4 o; o.x = f2bf(v.x); o.y = f2bf(v.y); o.z = f2bf(v.z); o.w = f2bf(v.w);
    dst[j * 64 + lane] = o;
  }
}

// ---- grouped GEMM: R3 verbatim (best measured: 121 us/pass) -----------------
template <int PASS>
__global__ __launch_bounds__(256, 2)
void gemm_kernel(const u16* __restrict__ A, const u16* __restrict__ WT,
                 const float* __restrict__ bias, const int* __restrict__ poff,
                 const int* __restrict__ ptok, const float* __restrict__ pgate,
                 u16* __restrict__ Hout, float* __restrict__ Out,
                 int* __restrict__ qhead) {
  __shared__ u16 As[2][128 * 64];
  __shared__ u16 Bs[2][128 * 64];
  __shared__ int tokS[128];
  __shared__ float gateS[128];
  __shared__ int tileS;

  const int tid = (int)threadIdx.x;
  const int lane = tid & 63;
  const int wid = tid >> 6;
  const int wm = (wid >> 1) * 64;
  const int wn = (wid & 1) * 64;
  const int r_in = lane >> 3;     // row within 8-row chunk
  const int s_phys = lane & 7;    // physical 16B slot

  const int total = (poff[NEXP] >> 7) * 8;

  for (;;) {
    if (tid == 0) tileS = atomicAdd(qhead, 1);
    __syncthreads();                       // publish tileS; fence prev epilogue
    const int tile = tileS;
    if (tile >= total) break;
    const int rt = tile >> 3;
    const int ct = tile & 7;
    const int row0 = rt * 128;
    int e = 0;
    while (row0 >= poff[e + 1]) ++e;       // 128-aligned segments: no spanning

    const u16* Ab = A + ((size_t)row0 << 10);
    const u16* Bb = WT + ((size_t)e << 20) + ((size_t)(ct * 128) << 10);

    if (PASS == 2 && tid < 128) {
      tokS[tid] = ptok[row0 + tid];
      gateS[tid] = pgate[row0 + tid];
    }

    f32x4 acc[4][4] = {};

#define STAGE(BUF, K0)                                                         \
  {                                                                            \
    _Pragma("unroll")                                                          \
    for (int i = 0; i < 4; ++i) {                                              \
      const int chunk = wid * 4 + i;                                           \
      const int row = chunk * 8 + r_in;                                        \
      const int slotL = s_phys ^ (row & 7);                                    \
      const size_t goff = ((size_t)row << 10) + (size_t)((K0) + slotL * 8);    \
      load16_lds(Ab + goff, &As[BUF][chunk * 512]);                            \
      load16_lds(Bb + goff, &Bs[BUF][chunk * 512]);                            \
    }                                                                          \
  }

#define COMPUTE(BUF)                                                           \
  {                                                                            \
    _Pragma("unroll")                                                          \
    for (int kk = 0; kk < 2; ++kk) {                                           \
      short8 af[4], bf_[4];                                                    \
      const int kslot = kk * 4 + (lane >> 4);                                  \
      _Pragma("unroll")                                                        \
      for (int mi = 0; mi < 4; ++mi) {                                         \
        const int m = wm + mi * 16 + (lane & 15);                              \
        af[mi] = *(const short8*)((const char*)&As[BUF][0] + m * 128 +         \
                                  ((kslot ^ (m & 7)) << 4));                   \
      }                                                                        \
      _Pragma("unroll")                                                        \
      for (int ni = 0; ni < 4; ++ni) {                                         \
        const int n = wn + ni * 16 + (lane & 15);                              \
        bf_[ni] = *(const short8*)((const char*)&Bs[BUF][0] + n * 128 +        \
                                   ((kslot ^ (n & 7)) << 4));                  \
      }                                                                        \
      _Pragma("unroll")                                                        \
      for (int mi = 0; mi < 4; ++mi)                                           \
        _Pragma("unroll")                                                      \
        for (int ni = 0; ni < 4; ++ni)                                         \
          acc[mi][ni] = __builtin_amdgcn_mfma_f32_16x16x32_bf16(               \
              af[mi], bf_[ni], acc[mi][ni], 0, 0, 0);                          \
    }                                                                          \
  }

    STAGE(0, 0)
#pragma unroll
    for (int t = 0; t < 16; ++t) {         // FULL unroll: const buffer indices
      if (t < 15) {
        STAGE((t + 1) & 1, (t + 1) * 64)   // issue next K-step's 8 loads
        asm volatile("s_waitcnt vmcnt(8)" ::: "memory");  // prev 8 landed
      } else {
        asm volatile("s_waitcnt vmcnt(0)" ::: "memory");
      }
      __builtin_amdgcn_s_barrier();        // all waves' buf[t&1] ready
      COMPUTE(t & 1)
      asm volatile("s_waitcnt lgkmcnt(0)" ::: "memory");
      __builtin_amdgcn_s_barrier();        // reads done; buf may be rewritten
    }

    // epilogue: C/D layout col = lane&15, row = (lane>>4)*4 + j  [m89/m91]
    const float* bb = bias + (e << 10) + ct * 128;
    const int cbase = lane & 15;
    const int rbase = (lane >> 4) * 4;
#pragma unroll
    for (int ni = 0; ni < 4; ++ni) {
      const int col = wn + ni * 16 + cbase;
      const float bv = bb[col];
#pragma unroll
      for (int mi = 0; mi < 4; ++mi) {
        const int mb = wm + mi * 16 + rbase;
#pragma unroll
        for (int j = 0; j < 4; ++j) {
          float v = fmaxf(acc[mi][ni][j] + bv, 0.0f);
          if (PASS == 1) {
            Hout[((size_t)(row0 + mb + j) << 10) + (size_t)(ct * 128 + col)] = f2bf(v);
          } else {
            const int m = mb + j;   // pad rows: gate==0 -> adds exactly 0
            unsafeAtomicAdd(Out + ((size_t)tokS[m] << 10) + (size_t)(ct * 128 + col),
                            v * gateS[m]);
          }
        }
      }
    }
#undef STAGE
#undef COMPUTE
  }
}

// ---- DIAGNOSTIC: stage+sync skeleton only, 96 K-steps, no compute ----------
// Same LDS footprint, same per-K-step load pattern, same vmcnt(8)+2-barrier
// skeleton as gemm_kernel, MFMA/ds_read/epilogue removed. 512 blocks = 2/CU
// (matches real occupancy). 96 steps = 6x the real 16 so its duration clears
// the ~121us real passes in the top-5 table iff stage-share >= ~37%.
// Writes one dead value to retired scratch (xp region, dead after pass 1).
__global__ __launch_bounds__(256, 2)
void diag_stage(const u16* __restrict__ A, const u16* __restrict__ WT,
                u16* __restrict__ scratch) {
  __shared__ u16 As[2][128 * 64];
  __shared__ u16 Bs[2][128 * 64];
  const int tid = (int)threadIdx.x;
  const int lane = tid & 63;
  const int wid = tid >> 6;
  const int r_in = lane >> 3;
  const int s_phys = lane & 7;
  const int bid = (int)blockIdx.x;
  // spread reads like the real kernel: 64 distinct A row-tiles, 8 experts
  const u16* Ab = A + ((size_t)((bid & 63) << 7) << 10);
  const u16* Wb = WT + ((size_t)(bid & 7) << 20) +
                  ((size_t)(((bid >> 3) & 7) << 7) << 10);

#define DSTAGE(BUF, K0)                                                        \
  {                                                                            \
    _Pragma("unroll")                                                          \
    for (int i = 0; i < 4; ++i) {                                              \
      const int chunk = wid * 4 + i;                                           \
      const int row = chunk * 8 + r_in;                                        \
      const int slotL = s_phys ^ (row & 7);                                    \
      const size_t goff = ((size_t)row << 10) + (size_t)((K0) + slotL * 8);    \
      load16_lds(Ab + goff, &As[BUF][chunk * 512]);                            \
      load16_lds(Wb + goff, &Bs[BUF][chunk * 512]);                            \
    }                                                                          \
  }

  DSTAGE(0, 0)
#pragma unroll 2
  for (int t = 0; t < 96; ++t) {
    if (t < 95) {
      DSTAGE((t + 1) & 1, (((t + 1) & 15)) * 64)
      asm volatile("s_waitcnt vmcnt(8)" ::: "memory");
    } else {
      asm volatile("s_waitcnt vmcnt(0)" ::: "memory");
    }
    __builtin_amdgcn_s_barrier();
    // compute elided (this is the ablation)
    __builtin_amdgcn_s_barrier();
  }
#undef DSTAGE
  // keep LDS state observable so nothing is DCE'd
  scratch[(size_t)bid * 256 + tid] = (u16)(As[0][tid] ^ Bs[1][tid]);
}

// ---- host-side launch ------------------------------------------------------
extern "C" void kernel_launch(void* const* d_in, const int* in_sizes, int n_in,
                              void* d_out, int out_size, void* d_ws, size_t ws_size,
                              hipStream_t stream) {
  (void)in_sizes; (void)n_in; (void)ws_size;
  const float* x  = (const float*)d_in[0];
  const float* W1 = (const float*)d_in[1];
  const float* b1 = (const float*)d_in[2];
  const float* W2 = (const float*)d_in[3];
  const float* b2 = (const float*)d_in[4];
  const float* Wg = (const float*)d_in[5];
  const float* bg = (const float*)d_in[6];
  float* out = (float*)d_out;
  char* ws = (char*)d_ws;

  u16*   W1T   = (u16*)(ws + OFF_W1T);
  u16*   W2T   = (u16*)(ws + OFF_W2T);
  u16*   xp    = (u16*)(ws + OFF_XP);
  u16*   h1    = (u16*)(ws + OFF_H1);
  int*   gidx  = (int*)(ws + OFF_GIDX);
  float* gval  = (float*)(ws + OFF_GVAL);
  int*   ptok  = (int*)(ws + OFF_PTOK);
  float* pgate = (float*)(ws + OFF_PGATE);
  int*   counts = (int*)(ws + OFF_CTRL);
  int*   cursor = counts + 8;
  int*   poff   = counts + 16;   // 9 ints
  int*   qh1    = counts + 25;
  int*   qh2    = counts + 26;

  hipMemsetAsync(d_out, 0, (size_t)out_size * 4, stream);
  hipMemsetAsync(ws + OFF_PTOK, 0, 139392, stream);

  convw_kernel<<<4096, 256, 0, stream>>>(W1, W2, W1T, W2T);
  gate_kernel<<<N_TOK / 4, 256, 0, stream>>>(x, Wg, bg, gidx, gval, counts);
  scan_kernel<<<1, 64, 0, stream>>>(counts, poff);
  scatter_kernel<<<N_TOK / 256, 256, 0, stream>>>(gidx, gval, poff, cursor, ptok, pgate);
  gather_kernel<<<PADROWS / 4, 256, 0, stream>>>(x, ptok, xp);
  gemm_kernel<1><<<MAXRT * 8, 256, 0, stream>>>(xp, W1T, b1, poff, ptok, pgate, h1, nullptr, qh1);
  gemm_kernel<2><<<MAXRT * 8, 256, 0, stream>>>(h1, W2T, b2, poff, ptok, pgate, nullptr, out, qh2);
  // diagnostic (reads xp which is dead after pass 1; writes dead scratch)
  diag_stage<<<512, 256, 0, stream>>>(xp, W1T, xp + (size_t)PADROWS * 1024 - 262144);
}

// Round 8
// 339.492 us; speedup vs baseline: 1.2412x; 1.1037x over previous
//
#include <hip/hip_runtime.h>
#include <stdint.h>

// ---- problem constants -----------------------------------------------------
#define N_TOK   8192
#define DIMK    1024      // D == H == 1024
#define NEXP    8
#define PADROWS 17408     // 16384 assignments + up to 8*128 padding, 128-aligned
#define MAXRT   136       // max row tiles of 128

typedef __attribute__((ext_vector_type(8))) short short8;   // 8 bf16 (4 VGPRs)
typedef __attribute__((ext_vector_type(4))) float f32x4;    // MFMA accumulator
typedef unsigned short u16;

__device__ __forceinline__ u16 f2bf(float f) {              // RNE f32->bf16
  uint32_t u = __builtin_bit_cast(uint32_t, f);
  u += 0x7fffu + ((u >> 16) & 1u);
  return (u16)(u >> 16);
}

__device__ __forceinline__ void load16_lds(const void* g, void* l) {
  __builtin_amdgcn_global_load_lds(
      (const __attribute__((address_space(1))) void*)g,
      (__attribute__((address_space(3))) void*)l, 16, 0, 0);
}

// ---- workspace layout (bytes) ----------------------------------------------
#define OFF_W1T   0u
#define OFF_W2T   16777216u
#define OFF_XP    33554432u
#define OFF_H1    69206016u
#define OFF_GIDX  104857600u
#define OFF_GVAL  104923136u
#define OFF_PTOK  104988672u
#define OFF_PGATE 105058304u
#define OFF_CTRL  105127936u
// zero region each launch: ptok + pgate + ctrl = 69632+69632+128 = 139392 B

// ---- W transpose+convert via LDS tile: WT[e][n][k] = bf16(W[e][k][n]) ------
__global__ void convw_kernel(const float* __restrict__ W1, const float* __restrict__ W2,
                             u16* __restrict__ W1T, u16* __restrict__ W2T) {
  __shared__ u16 tile[64][65];
  int b = (int)blockIdx.x;
  const float* src = W1; u16* dst = W1T;
  if (b >= 2048) { src = W2; dst = W2T; b -= 2048; }
  const int e  = b >> 8;
  const int t  = b & 255;
  const int k0 = (t >> 4) << 6;
  const int n0 = (t & 15) << 6;
  const int tid = (int)threadIdx.x;
  const int r  = tid >> 2;
  const int c4 = (tid & 3) << 4;
  const float4* s = (const float4*)(src + ((size_t)e << 20) +
                                    ((size_t)(k0 + r) << 10) + n0 + c4);
#pragma unroll
  for (int j = 0; j < 4; ++j) {
    float4 v = s[j];
    tile[r][c4 + 4 * j + 0] = f2bf(v.x);
    tile[r][c4 + 4 * j + 1] = f2bf(v.y);
    tile[r][c4 + 4 * j + 2] = f2bf(v.z);
    tile[r][c4 + 4 * j + 3] = f2bf(v.w);
  }
  __syncthreads();
  const int on = tid >> 2;
  const int ok = (tid & 3) << 4;
  u16* d = dst + ((size_t)e << 20) + ((size_t)(n0 + on) << 10) + k0 + ok;
  short8 v0, v1;
#pragma unroll
  for (int j = 0; j < 8; ++j) {
    v0[j] = (short)tile[ok + j][on];
    v1[j] = (short)tile[ok + 8 + j][on];
  }
  *(short8*)d = v0;
  *(short8*)(d + 8) = v1;
}

// ---- gating: f32 logits, top-2 (jax tie-break), softmax, histogram ---------
__global__ void gate_kernel(const float* __restrict__ x, const float* __restrict__ Wg,
                            const float* __restrict__ bg, int* __restrict__ gidx,
                            float* __restrict__ gval, int* __restrict__ counts) {
  __shared__ int hist[NEXP];
  const int tid = (int)threadIdx.x;
  if (tid < NEXP) hist[tid] = 0;
  __syncthreads();
  const int n = (int)blockIdx.x * 4 + (tid >> 6);
  const int lane = tid & 63;
  float acc[NEXP];
#pragma unroll
  for (int e = 0; e < NEXP; ++e) acc[e] = 0.f;
  const float4* xr = (const float4*)(x + ((size_t)n << 10));
#pragma unroll
  for (int j = 0; j < 4; ++j) {
    float4 xv = xr[j * 64 + lane];
#pragma unroll
    for (int e = 0; e < NEXP; ++e) {
      float4 wv = ((const float4*)(Wg + ((size_t)e << 10)))[j * 64 + lane];
      acc[e] += xv.x * wv.x + xv.y * wv.y + xv.z * wv.z + xv.w * wv.w;
    }
  }
#pragma unroll
  for (int e = 0; e < NEXP; ++e)
#pragma unroll
    for (int off = 32; off; off >>= 1) acc[e] += __shfl_xor(acc[e], off, 64);
  if (lane == 0) {
    float lg[NEXP];
#pragma unroll
    for (int e = 0; e < NEXP; ++e) lg[e] = acc[e] + bg[e];
    int e0 = 0; float v0 = lg[0];
#pragma unroll
    for (int e = 1; e < NEXP; ++e) if (lg[e] > v0) { v0 = lg[e]; e0 = e; }
    int e1 = -1; float v1 = -1e30f;
#pragma unroll
    for (int e = 0; e < NEXP; ++e) if (e != e0 && lg[e] > v1) { v1 = lg[e]; e1 = e; }
    float t = expf(v1 - v0);            // v0 >= v1
    float g0 = 1.f / (1.f + t);
    gidx[2 * n] = e0; gidx[2 * n + 1] = e1;
    gval[2 * n] = g0; gval[2 * n + 1] = t * g0;
    atomicAdd(&hist[e0], 1); atomicAdd(&hist[e1], 1);
  }
  __syncthreads();
  if (tid < NEXP && hist[tid]) atomicAdd(&counts[tid], hist[tid]);
}

// ---- scan: 128-aligned segment offsets -------------------------------------
__global__ void scan_kernel(const int* __restrict__ counts, int* __restrict__ poff) {
  if (threadIdx.x == 0) {
    int off = 0; poff[0] = 0;
    for (int e = 0; e < NEXP; ++e) { off += ((counts[e] + 127) >> 7) << 7; poff[e + 1] = off; }
  }
}

// ---- scatter assignments into expert segments ------------------------------
__global__ void scatter_kernel(const int* __restrict__ gidx, const float* __restrict__ gval,
                               const int* __restrict__ poff, int* __restrict__ cursor,
                               int* __restrict__ ptok, float* __restrict__ pgate) {
  const int n = (int)blockIdx.x * 256 + (int)threadIdx.x;
#pragma unroll
  for (int k = 0; k < 2; ++k) {
    const int e = gidx[2 * n + k];
    const int p = poff[e] + atomicAdd(&cursor[e], 1);
    ptok[p] = n;
    pgate[p] = gval[2 * n + k];
  }
}

// ---- gather x rows (permuted) -> bf16 --------------------------------------
__global__ void gather_kernel(const float* __restrict__ x, const int* __restrict__ ptok,
                              u16* __restrict__ xp) {
  const int p = (int)blockIdx.x * 4 + ((int)threadIdx.x >> 6);
  const int lane = (int)threadIdx.x & 63;
  const int tok = ptok[p];
  const float4* src = (const float4*)(x + ((size_t)tok << 10));
  ushort4* dst = (ushort4*)(xp + ((size_t)p << 10));
#pragma unroll
  for (int j = 0; j < 4; ++j) {
    float4 v = src[j * 64 + lane];
    ushort4 o; o.x = f2bf(v.x); o.y = f2bf(v.y); o.z = f2bf(v.z); o.w = f2bf(v.w);
    dst[j * 64 + lane] = o;
  }
}

// ---- grouped GEMM: 128x128 tile, BK=32, FOUR LDS buffers, depth-3 vmcnt ----
// R7 = R6 with the LDS OOB fixed: chunk stride is 512 u16 (16 rows x 32 u16 =
// 64 lanes x 16B), NOT 1024. R6's chunk*1024 wrote past the LDS allocation ->
// memory fault -> abort.
// Design (unchanged): prefetch depth 1 -> 3 (T4, m218's counted-vmcnt lever).
// Per K-step (32 K): STAGE(t+3) then vmcnt(12) — step t's 4 loads landed,
// 12 loads (t+1..t+3) stay in flight ACROSS the barriers. Buffer safety is
// static: buf[(t+3)&3] was last read in step t-1, whose lgkmcnt(0)+barrier
// precede this stage issue. No spins; all waits compile-time (full unroll).
// Swizzle (both-sides, 4 slots/row): phys_slot = log_slot ^ ((row>>1)&3);
// stage pre-swizzles the GLOBAL source slot (gload_lds dest stays linear),
// reads XOR the same term. Bank check: <=2-way (free, m136).
template <int PASS>
__global__ __launch_bounds__(256, 2)
void gemm_kernel(const u16* __restrict__ A, const u16* __restrict__ WT,
                 const float* __restrict__ bias, const int* __restrict__ poff,
                 const int* __restrict__ ptok, const float* __restrict__ pgate,
                 u16* __restrict__ Hout, float* __restrict__ Out,
                 int* __restrict__ qhead) {
  __shared__ u16 As[4][128 * 32];
  __shared__ u16 Bs[4][128 * 32];
  __shared__ int tokS[128];
  __shared__ float gateS[128];
  __shared__ int tileS;

  const int tid = (int)threadIdx.x;
  const int lane = tid & 63;
  const int wid = tid >> 6;
  const int wm = (wid >> 1) * 64;
  const int wn = (wid & 1) * 64;
  // stage addressing: lane covers row chunk*16+(lane>>2), physical slot lane&3
  const int st_row = lane >> 2;
  const int st_slot = ((lane & 3) ^ ((lane >> 3) & 3)) * 8;  // pre-swizzled src (u16)
  // read addressing: logical k-slot lane>>4, row-swizzle ((row>>1)&3)=((lane>>1)&3)
  const int rdslot = (((lane >> 4) ^ ((lane >> 1) & 3)) * 8); // u16 units

  const int total = (poff[NEXP] >> 7) * 8;

  for (;;) {
    if (tid == 0) tileS = atomicAdd(qhead, 1);
    __syncthreads();                       // publish tileS; fence prev epilogue
    const int tile = tileS;
    if (tile >= total) break;
    const int rt = tile >> 3;
    const int ct = tile & 7;
    const int row0 = rt * 128;
    int e = 0;
    while (row0 >= poff[e + 1]) ++e;       // 128-aligned segments: no spanning

    const u16* Ab = A + ((size_t)row0 << 10);
    const u16* Bb = WT + ((size_t)e << 20) + ((size_t)(ct * 128) << 10);

    if (PASS == 2 && tid < 128) {
      tokS[tid] = ptok[row0 + tid];
      gateS[tid] = pgate[row0 + tid];
    }

    f32x4 acc[4][4] = {};

// stage one 128x32 K-slab of A and B into buffer BUF (4 loads/thread).
// chunk = 16 rows x 32 u16 = 512 u16 = 64 lanes x 16B  (FIXED: was *1024)
#define STAGE(BUF, T)                                                          \
  {                                                                            \
    _Pragma("unroll")                                                          \
    for (int j = 0; j < 2; ++j) {                                              \
      const int chunk = wid * 2 + j;        /* 8 chunks x 16 rows */           \
      const int row = chunk * 16 + st_row;                                     \
      const size_t goff = ((size_t)row << 10) + (size_t)((T) * 32 + st_slot);  \
      load16_lds(Ab + goff, &As[BUF][chunk * 512]);                            \
      load16_lds(Bb + goff, &Bs[BUF][chunk * 512]);                            \
    }                                                                          \
  }

#define COMPUTE(BUF)                                                           \
  {                                                                            \
    short8 af[4], bf_[4];                                                      \
    _Pragma("unroll")                                                          \
    for (int mi = 0; mi < 4; ++mi) {                                           \
      const int m = wm + mi * 16 + (lane & 15);                                \
      af[mi] = *(const short8*)(&As[BUF][m * 32 + rdslot]);                    \
    }                                                                          \
    _Pragma("unroll")                                                          \
    for (int ni = 0; ni < 4; ++ni) {                                           \
      const int n = wn + ni * 16 + (lane & 15);                                \
      bf_[ni] = *(const short8*)(&Bs[BUF][n * 32 + rdslot]);                   \
    }                                                                          \
    _Pragma("unroll")                                                          \
    for (int mi = 0; mi < 4; ++mi)                                             \
      _Pragma("unroll")                                                        \
      for (int ni = 0; ni < 4; ++ni)                                           \
        acc[mi][ni] = __builtin_amdgcn_mfma_f32_16x16x32_bf16(                 \
            af[mi], bf_[ni], acc[mi][ni], 0, 0, 0);                            \
  }

    STAGE(0, 0) STAGE(1, 1) STAGE(2, 2)    // 12 loads/thread in flight
#pragma unroll
    for (int t = 0; t < 32; ++t) {         // FULL unroll: const buf indices
      if (t < 29) {
        STAGE((t + 3) & 3, t + 3)          // depth-3 prefetch (16 in flight)
        asm volatile("s_waitcnt vmcnt(12)" ::: "memory");   // stage(t) landed
      } else if (t == 29) {
        asm volatile("s_waitcnt vmcnt(8)" ::: "memory");
      } else if (t == 30) {
        asm volatile("s_waitcnt vmcnt(4)" ::: "memory");
      } else {
        asm volatile("s_waitcnt vmcnt(0)" ::: "memory");
      }
      __builtin_amdgcn_s_barrier();        // all waves' buf[t&3] ready
      COMPUTE(t & 3)
      asm volatile("s_waitcnt lgkmcnt(0)" ::: "memory");
      __builtin_amdgcn_s_barrier();        // reads done; buf restaged at t+1
    }

    // epilogue: C/D layout col = lane&15, row = (lane>>4)*4 + j  [m89/m91]
    const float* bb = bias + (e << 10) + ct * 128;
    const int cbase = lane & 15;
    const int rbase = (lane >> 4) * 4;
#pragma unroll
    for (int ni = 0; ni < 4; ++ni) {
      const int col = wn + ni * 16 + cbase;
      const float bv = bb[col];
#pragma unroll
      for (int mi = 0; mi < 4; ++mi) {
        const int mb = wm + mi * 16 + rbase;
#pragma unroll
        for (int j = 0; j < 4; ++j) {
          float v = fmaxf(acc[mi][ni][j] + bv, 0.0f);
          if (PASS == 1) {
            Hout[((size_t)(row0 + mb + j) << 10) + (size_t)(ct * 128 + col)] = f2bf(v);
          } else {
            const int m = mb + j;   // pad rows: gate==0 -> adds exactly 0
            unsafeAtomicAdd(Out + ((size_t)tokS[m] << 10) + (size_t)(ct * 128 + col),
                            v * gateS[m]);
          }
        }
      }
    }
#undef STAGE
#undef COMPUTE
  }
}

// ---- host-side launch ------------------------------------------------------
extern "C" void kernel_launch(void* const* d_in, const int* in_sizes, int n_in,
                              void* d_out, int out_size, void* d_ws, size_t ws_size,
                              hipStream_t stream) {
  (void)in_sizes; (void)n_in; (void)ws_size;
  const float* x  = (const float*)d_in[0];
  const float* W1 = (const float*)d_in[1];
  const float* b1 = (const float*)d_in[2];
  const float* W2 = (const float*)d_in[3];
  const float* b2 = (const float*)d_in[4];
  const float* Wg = (const float*)d_in[5];
  const float* bg = (const float*)d_in[6];
  float* out = (float*)d_out;
  char* ws = (char*)d_ws;

  u16*   W1T   = (u16*)(ws + OFF_W1T);
  u16*   W2T   = (u16*)(ws + OFF_W2T);
  u16*   xp    = (u16*)(ws + OFF_XP);
  u16*   h1    = (u16*)(ws + OFF_H1);
  int*   gidx  = (int*)(ws + OFF_GIDX);
  float* gval  = (float*)(ws + OFF_GVAL);
  int*   ptok  = (int*)(ws + OFF_PTOK);
  float* pgate = (float*)(ws + OFF_PGATE);
  int*   counts = (int*)(ws + OFF_CTRL);
  int*   cursor = counts + 8;
  int*   poff   = counts + 16;   // 9 ints
  int*   qh1    = counts + 25;
  int*   qh2    = counts + 26;

  hipMemsetAsync(d_out, 0, (size_t)out_size * 4, stream);
  hipMemsetAsync(ws + OFF_PTOK, 0, 139392, stream);

  convw_kernel<<<4096, 256, 0, stream>>>(W1, W2, W1T, W2T);
  gate_kernel<<<N_TOK / 4, 256, 0, stream>>>(x, Wg, bg, gidx, gval, counts);
  scan_kernel<<<1, 64, 0, stream>>>(counts, poff);
  scatter_kernel<<<N_TOK / 256, 256, 0, stream>>>(gidx, gval, poff, cursor, ptok, pgate);
  gather_kernel<<<PADROWS / 4, 256, 0, stream>>>(x, ptok, xp);
  gemm_kernel<1><<<MAXRT * 8, 256, 0, stream>>>(xp, W1T, b1, poff, ptok, pgate, h1, nullptr, qh1);
  gemm_kernel<2><<<MAXRT * 8, 256, 0, stream>>>(h1, W2T, b2, poff, ptok, pgate, nullptr, out, qh2);
}